// Round 5
// baseline (382.768 us; speedup 1.0000x reference)
//
#include <hip/hip_runtime.h>

#define N_NODES 100000
#define N_EDGES 1600000
#define D 64
#define NBUCK 3125             // 32-node buckets: col>>5
#define NBP 3136               // padded bucket count (LDS arrays / strides)
#define NBLK 128               // edge-partition blocks for count/scatter
#define EPB 12500              // edges per count/scatter block
#define CAP 1024               // records per in-LDS chunk in gather
#define AST 68                 // padded LDS row stride in floats

// -------- K0: x (fp32) -> xh (bf16, RNE); zero deg shadows + btot ---------
__device__ __forceinline__ unsigned bf16rne(float f) {
    unsigned u = __float_as_uint(f);
    return (u + 0x7FFFu + ((u >> 16) & 1u)) >> 16;
}
__global__ __launch_bounds__(256) void tobf16_kernel(const float* __restrict__ x,
                                                     ushort* __restrict__ xh,
                                                     float* __restrict__ deg4,
                                                     int* __restrict__ btot) {
    int id = blockIdx.x * 256 + threadIdx.x;       // 800k threads
    if (id < 4 * N_NODES) deg4[id] = 0.f;
    if (id < NBUCK) btot[id] = 0;
    int i = id * 8;                                // 6.4M bf16 elems / 8
    float4 a = *(const float4*)(x + i);
    float4 b = *(const float4*)(x + i + 4);
    uint4 o;
    o.x = bf16rne(a.x) | (bf16rne(a.y) << 16);
    o.y = bf16rne(a.z) | (bf16rne(a.w) << 16);
    o.z = bf16rne(b.x) | (bf16rne(b.y) << 16);
    o.w = bf16rne(b.z) | (bf16rne(b.w) << 16);
    *(uint4*)(xh + i) = o;
}

// -------- K1: per-block 3125-bucket col histogram + deg shadow atomics ----
// cntM[b][j] (stride NBP): coalesced writes here, coalesced reads in K3a.
__global__ __launch_bounds__(512) void countdeg_kernel(const int* __restrict__ row,
                                                       const int* __restrict__ col,
                                                       const float* __restrict__ w,
                                                       float* __restrict__ deg4,
                                                       int* __restrict__ cntM,
                                                       int* __restrict__ btot) {
    __shared__ int h[NBP];                          // 12.5 KB
    int t = threadIdx.x;
    int b = blockIdx.x;
    for (int j = t; j < NBP; j += 512) h[j] = 0;
    __syncthreads();
    int base = b * EPB;
    float* dg = deg4 + (size_t)(b & 3) * N_NODES;
    for (int i = t; i < EPB; i += 512) {
        int e = base + i;
        atomicAdd(&dg[row[e]], w[e]);              // fire-and-forget, 4 shadows
        atomicAdd(&h[col[e] >> 5], 1);
    }
    __syncthreads();
    int* mc = cntM + (size_t)b * NBP;
    for (int j = t; j < NBUCK; j += 512) {
        int v = h[j];
        mc[j] = v;                                 // coalesced
        if (v) atomicAdd(&btot[j], v);
    }
}

// -------- K2: exclusive scan of 3125 bucket totals (one block, carried) ---
__global__ __launch_bounds__(512) void scanTot_kernel(const int* __restrict__ btot,
                                                      int* __restrict__ cbase) {
    __shared__ int sc[512];
    int t = threadIdx.x;
    int carry = 0;
    for (int c0 = 0; c0 < NBUCK; c0 += 512) {
        int idx = c0 + t;
        int v = (idx < NBUCK) ? btot[idx] : 0;
        sc[t] = v;
        __syncthreads();
        for (int off = 1; off < 512; off <<= 1) {
            int u = (t >= off) ? sc[t - off] : 0;
            __syncthreads();
            sc[t] += u;
            __syncthreads();
        }
        if (idx < NBUCK) cbase[idx] = carry + sc[t] - v;
        int top = sc[511];
        __syncthreads();                           // top read before next overwrite
        carry += top;
    }
    if (t == 0) cbase[NBUCK] = N_EDGES;
}

// -------- K3: per-bucket scan over the 128 block counts + dinv ------------
__global__ __launch_bounds__(128) void scanD_kernel(const int* __restrict__ cbase,
                                                    int* __restrict__ cntM,
                                                    const float* __restrict__ deg4,
                                                    float* __restrict__ dinv) {
    __shared__ int w0tot;
    int j = blockIdx.x;          // bucket 0..3124
    int t = threadIdx.x;         // edge-block index 0..127
    int v = cntM[(size_t)t * NBP + j];
    int lane = t & 63;
    int inc = v;
    #pragma unroll
    for (int d = 1; d < 64; d <<= 1) {
        int u = __shfl_up(inc, d, 64);
        if (lane >= d) inc += u;
    }
    if (t == 63) w0tot = inc;
    __syncthreads();
    int off = (t >= 64) ? w0tot : 0;
    cntM[(size_t)t * NBP + j] = cbase[j] + off + inc - v;
    if (t < 32) {                // dinv for this bucket's 32 nodes
        int n = j * 32 + t;
        float d = deg4[n] + deg4[N_NODES + n] + deg4[2 * N_NODES + n]
                + deg4[3 * N_NODES + n];
        dinv[n] = d > 0.f ? rsqrtf(d) : 0.f;
    }
}

// -------- K4: deterministic scatter, dinv folded --------------------------
// rec = { (coloff5<<17)|row17 , float cf = w*dinv[row] }
__global__ __launch_bounds__(512) void scatterA_kernel(const int* __restrict__ row,
                                                       const int* __restrict__ col,
                                                       const float* __restrict__ w,
                                                       const float* __restrict__ dinv,
                                                       const int* __restrict__ cntM,
                                                       int2* __restrict__ recA) {
    __shared__ int curs[NBP];                       // 12.5 KB
    int t = threadIdx.x;
    int b = blockIdx.x;
    const int* mc = cntM + (size_t)b * NBP;
    for (int j = t; j < NBUCK; j += 512) curs[j] = mc[j];  // coalesced
    __syncthreads();
    int base = b * EPB;
    for (int i = t; i < EPB; i += 512) {
        int e = base + i;
        int r = row[e];
        int c = col[e];
        float cf = w[e] * dinv[r];                 // dinv: 400KB, L2-resident
        int p = atomicAdd(&curs[c >> 5], 1);       // LDS atomic only
        recA[p] = make_int2(((c & 31) << 17) | r, __float_as_int(cf));
    }
}

#define FMA_BF16(e, u)                                                         \
    do { float cc = __int_as_float((e).y);                                     \
        acc0.x += cc * __uint_as_float((u).x << 16);                           \
        acc0.y += cc * __uint_as_float((u).x & 0xFFFF0000u);                   \
        acc0.z += cc * __uint_as_float((u).y << 16);                           \
        acc0.w += cc * __uint_as_float((u).y & 0xFFFF0000u);                   \
        acc1.x += cc * __uint_as_float((u).z << 16);                           \
        acc1.y += cc * __uint_as_float((u).z & 0xFFFF0000u);                   \
        acc1.z += cc * __uint_as_float((u).w << 16);                           \
        acc1.w += cc * __uint_as_float((u).w & 0xFFFF0000u);                   \
    } while (0)

// -------- K5: chunk-staged sort + register gather (bf16 x) + matmul -------
// Block = one bucket of 32 nodes; 256 threads = 32 node-groups x 8 lanes.
// Round-0-proven structure; records arrive pre-folded (no dinv/dequant here).
__global__ __launch_bounds__(256, 8) void gather_out_kernel(
        const int2* __restrict__ recA, const int* __restrict__ cbase,
        const float* __restrict__ dinv, const ushort* __restrict__ xh,
        const float* __restrict__ x, const float* __restrict__ W0,
        const float* __restrict__ W1, const float* __restrict__ bias,
        float* __restrict__ out) {
    __shared__ __align__(16) char smemA[32 * AST * 4];  // srt (8192B) | xs (8704B)
    __shared__ __align__(16) char smemB[32 * AST * 4];  // stg (8192B) | ts (8704B)
    __shared__ int cnt32[32];
    __shared__ int start32[32];
    __shared__ int cur32[32];
    int2*  srt = (int2*)smemA;
    float* xs  = (float*)smemA;
    int2*  stg = (int2*)smemB;
    float* ts  = (float*)smemB;

    int tid = threadIdx.x;
    int b   = blockIdx.x;
    int n0  = b * 32;
    int g   = tid >> 3;      // node within bucket
    int j   = tid & 7;       // lane owns features 8j..8j+7

    int base = cbase[b];
    int cnt  = cbase[b + 1] - base;

    float4 acc0 = make_float4(0.f, 0.f, 0.f, 0.f);
    float4 acc1 = make_float4(0.f, 0.f, 0.f, 0.f);
    const ushort* xhj = xh + (j << 3);

    for (int cb = 0; cb < cnt; cb += CAP) {
        int m = min(CAP, cnt - cb);
        if (tid < 32) cnt32[tid] = 0;
        __syncthreads();
        // stage records into LDS; histogram fused into the staging loop
        for (int i = tid; i < m; i += 256) {
            int2 rc = recA[base + cb + i];         // coalesced 8B
            stg[i] = rc;
            atomicAdd(&cnt32[(rc.x >> 17) & 31], 1);
        }
        __syncthreads();
        if (tid < 32) {               // exclusive scan via shfl (wave 0)
            int v = cnt32[tid];
            int inc = v;
            #pragma unroll
            for (int d = 1; d < 32; d <<= 1) {
                int u = __shfl_up(inc, d, 32);
                if (tid >= d) inc += u;
            }
            start32[tid] = inc - v;
            cur32[tid]   = inc - v;
        }
        __syncthreads();
        // place into node order (LDS only)
        for (int i = tid; i < m; i += 256) {
            int2 rc = stg[i];
            int p = atomicAdd(&cur32[(rc.x >> 17) & 31], 1);
            srt[p] = make_int2(rc.x & 0x1FFFF, rc.y);
        }
        __syncthreads();
        // per-node accumulation from bf16 rows (1 uint4 = 8 features / edge)
        int ks = start32[g];
        int ke = cur32[g];
        int k = ks;
        for (; k + 3 < ke; k += 4) {
            int2 e0 = srt[k + 0];
            int2 e1 = srt[k + 1];
            int2 e2 = srt[k + 2];
            int2 e3 = srt[k + 3];
            uint4 u0 = *(const uint4*)(xhj + ((size_t)e0.x << 6));
            uint4 u1 = *(const uint4*)(xhj + ((size_t)e1.x << 6));
            uint4 u2 = *(const uint4*)(xhj + ((size_t)e2.x << 6));
            uint4 u3 = *(const uint4*)(xhj + ((size_t)e3.x << 6));
            FMA_BF16(e0, u0);
            FMA_BF16(e1, u1);
            FMA_BF16(e2, u2);
            FMA_BF16(e3, u3);
        }
        for (; k < ke; ++k) {
            int2 e0 = srt[k];
            uint4 u0 = *(const uint4*)(xhj + ((size_t)e0.x << 6));
            FMA_BF16(e0, u0);
        }
        __syncthreads();   // srt/stg reads done before next chunk / xs,ts overwrite
    }

    // Epilogue: ts = -dinv[n]*acc, stage xs (fp32), matmul.
    float dn = -dinv[n0 + g];
    float* tp = ts + g * AST + (j << 3);
    *(float4*)tp       = make_float4(dn * acc0.x, dn * acc0.y, dn * acc0.z, dn * acc0.w);
    *(float4*)(tp + 4) = make_float4(dn * acc1.x, dn * acc1.y, dn * acc1.z, dn * acc1.w);
    for (int i = tid; i < 512; i += 256) {          // 512 float4 = 32x64 floats
        int nn = i >> 4;
        int kk = (i & 15) << 2;
        *(float4*)&xs[nn * AST + kk] = *(const float4*)(x + (size_t)n0 * D + i * 4);
    }
    __syncthreads();

    int jl = j << 3;
    float4 o0 = *(const float4*)(bias + jl);
    float4 o1 = *(const float4*)(bias + jl + 4);
    for (int k2 = 0; k2 < D; k2 += 4) {
        float4 av = *(const float4*)&xs[g * AST + k2];
        float4 tv = *(const float4*)&ts[g * AST + k2];
        #pragma unroll
        for (int u = 0; u < 4; ++u) {
            float a = (u == 0) ? av.x : (u == 1) ? av.y : (u == 2) ? av.z : av.w;
            float t = (u == 0) ? tv.x : (u == 1) ? tv.y : (u == 2) ? tv.z : tv.w;
            const float4 w00 = *(const float4*)(W0 + (size_t)(k2 + u) * D + jl);
            const float4 w01 = *(const float4*)(W0 + (size_t)(k2 + u) * D + jl + 4);
            const float4 w10 = *(const float4*)(W1 + (size_t)(k2 + u) * D + jl);
            const float4 w11 = *(const float4*)(W1 + (size_t)(k2 + u) * D + jl + 4);
            o0.x += a * w00.x + t * w10.x;
            o0.y += a * w00.y + t * w10.y;
            o0.z += a * w00.z + t * w10.z;
            o0.w += a * w00.w + t * w10.w;
            o1.x += a * w01.x + t * w11.x;
            o1.y += a * w01.y + t * w11.y;
            o1.z += a * w01.z + t * w11.z;
            o1.w += a * w01.w + t * w11.w;
        }
    }
    float* op = out + (size_t)(n0 + g) * D + jl;
    *(float4*)op       = o0;
    *(float4*)(op + 4) = o1;
}

extern "C" void kernel_launch(void* const* d_in, const int* in_sizes, int n_in,
                              void* d_out, int out_size, void* d_ws, size_t ws_size,
                              hipStream_t stream) {
    const float* x    = (const float*)d_in[0];
    const int*   eidx = (const int*)d_in[1];   // [2, E]: row then col (int32)
    const float* ew   = (const float*)d_in[2];
    const float* W0   = (const float*)d_in[3];
    const float* W1   = (const float*)d_in[4];
    const float* b    = (const float*)d_in[5];
    float* out = (float*)d_out;

    const int* row = eidx;
    const int* col = eidx + N_EDGES;

    // Workspace (4B words), fully overwritten each call:
    // recA 12.8MB | cntM 1.6MB | btot 12.8KB | cbase 12.8KB | deg4 1.6MB |
    // dinv 0.4MB | xh 12.8MB  ~= 29.3MB
    int2*   recA  = (int2*)d_ws;                               // E int2
    int*    cntM  = (int*)(recA + N_EDGES);                    // NBLK*NBP
    int*    btot  = cntM + (size_t)NBLK * NBP;                 // NBUCK (pad 3200)
    int*    cbase = btot + 3200;                               // NBUCK+1 (pad 3200)
    float*  deg4  = (float*)(cbase + 3200);                    // 4*N
    float*  dinv  = deg4 + 4 * N_NODES;                        // N
    ushort* xh    = (ushort*)(dinv + N_NODES);                 // N*D ushort

    tobf16_kernel   <<<N_NODES * D / (256 * 8), 256, 0, stream>>>(x, xh, deg4, btot);
    countdeg_kernel <<<NBLK, 512, 0, stream>>>(row, col, ew, deg4, cntM, btot);
    scanTot_kernel  <<<1, 512, 0, stream>>>(btot, cbase);
    scanD_kernel    <<<NBUCK, 128, 0, stream>>>(cbase, cntM, deg4, dinv);
    scatterA_kernel <<<NBLK, 512, 0, stream>>>(row, col, ew, dinv, cntM, recA);
    gather_out_kernel<<<NBUCK, 256, 0, stream>>>(recA, cbase, dinv,
                                                 xh, x, W0, W1, b, out);
}